// Round 2
// baseline (3270.274 us; speedup 1.0000x reference)
//
#include <hip/hip_runtime.h>

// HierarchicalGraphNet: N=100000 nodes, E=320000 edges, D=256, L=3, G=4096.
#define N_NODES 100000
#define N_EDGES 320000
#define N_GRAPH 4096
#define M_PAD   100096                   // N padded to multiple of 128
#define N_TILES 782                      // M_PAD / 128
#define LN_EPS  1e-5f
#define S_EL    ((size_t)M_PAD * 256)    // elements per full M x 256 plane
#define OENC_B  ((size_t)N_GRAPH * 512 * 4)   // m|e encoded maxima only
#define CAP     32                       // in-edge bucket capacity per node

typedef __attribute__((ext_vector_type(8))) short short8;   // 8 x bf16 MFMA operand
typedef __attribute__((ext_vector_type(4))) float f32x4;    // MFMA accumulator
typedef unsigned short u16;

__device__ __forceinline__ float bf2f(u16 u){
  return __uint_as_float(((unsigned)u) << 16);
}
__device__ __forceinline__ u16 f2bf(float f){   // RNE round
  unsigned u = __float_as_uint(f);
  return (u16)((u + 0x7FFFu + ((u >> 16) & 1u)) >> 16);
}
// external float tensor read: fp32 or bf16 per runtime flag
__device__ __forceinline__ float ldext(const void* p, long i, bool f32){
  return f32 ? ((const float*)p)[i] : bf2f(((const u16*)p)[i]);
}
// order-preserving float<->uint encoding for atomicMax-based segment_max
__device__ __forceinline__ unsigned enc_f(float f){
  unsigned u = __float_as_uint(f);
  return (u & 0x80000000u) ? ~u : (u | 0x80000000u);
}
__device__ __forceinline__ float dec_f(unsigned e){
  unsigned u = (e & 0x80000000u) ? (e & 0x7FFFFFFFu) : ~e;
  return __uint_as_float(u);
}
__device__ __forceinline__ float sigm(float x){ return 1.0f/(1.0f + __expf(-x)); }
__device__ __forceinline__ void ld4bf(const u16* p, float* o){
  ushort4 v = *(const ushort4*)p;
  o[0]=bf2f(v.x); o[1]=bf2f(v.y); o[2]=bf2f(v.z); o[3]=bf2f(v.w);
}

// swizzled byte offset inside one 64 KB A-tile (128 rows x 256 bf16, row=512B)
// XOR row bits into byte-addr bits [4..6]: kills the 16-way bank conflict of
// row-strided ds_read_b128 (G4), bijective per 8-row stripe.
__device__ __forceinline__ int swzb(int row, int colByte){
  return (row << 9) + (colByte ^ ((row & 7) << 4));
}

// ---- dtype detector ---------------------------------------------------------
__global__ void k_detect(const unsigned* __restrict__ x32, int* __restrict__ flag){
  unsigned u = x32[threadIdx.x];            // 64 threads
  int ef = (int)((u >> 23) & 0xFFu);
  int ok = (ef >= 64 && ef <= 190) ? 1 : 0;
  #pragma unroll
  for (int o=1; o<64; o<<=1) ok += __shfl_xor(ok, o);
  if (threadIdx.x == 0) *flag = (ok >= 32) ? 1 : 0;
}

// ---- init kernels -----------------------------------------------------------
__global__ void k_h_init(const void* __restrict__ x, u16* __restrict__ h,
                         const int* __restrict__ dflag){
  const bool f32 = (*dflag != 0);
  int i = blockIdx.x*256 + threadIdx.x;     // 8 elements per thread
  size_t base = (size_t)i*8;
  int n = (int)(base >> 8);
  uint4 v = make_uint4(0,0,0,0);
  if (n < N_NODES){
    if (f32){
      const float* xf = (const float*)x + base;
      float4 a = *(const float4*)xf;
      float4 b = *(const float4*)(xf + 4);
      ushort4 lo = make_ushort4(f2bf(a.x),f2bf(a.y),f2bf(a.z),f2bf(a.w));
      ushort4 hi = make_ushort4(f2bf(b.x),f2bf(b.y),f2bf(b.z),f2bf(b.w));
      v.x = (unsigned)lo.x | ((unsigned)lo.y<<16);
      v.y = (unsigned)lo.z | ((unsigned)lo.w<<16);
      v.z = (unsigned)hi.x | ((unsigned)hi.y<<16);
      v.w = (unsigned)hi.z | ((unsigned)hi.w<<16);
    } else {
      v = *(const uint4*)((const u16*)x + base);
    }
  }
  *(uint4*)&h[base] = v;
}

// ---- inverse-CSR bucket build (edges are static across layers) --------------
__global__ void k_bucket_build(const int* __restrict__ ei, int* __restrict__ cnt,
                               int* __restrict__ bucket, int* __restrict__ ovf,
                               int* __restrict__ ovfcnt){
  int e = blockIdx.x*256 + threadIdx.x;
  if (e >= N_EDGES) return;
  int s = ei[e];
  int d = ei[N_EDGES + e];
  int pos = atomicAdd(&cnt[d], 1);
  if (pos < CAP) bucket[(size_t)d*CAP + pos] = s;
  else { int o = atomicAdd(ovfcnt, 1); ovf[o] = e; }  // o < E always
}

// ---- atomic-free GIN aggregation: G[n] = h[n] + sum_{s->n} h[s] -------------
__global__ __launch_bounds__(256) void k_gather(
    const unsigned* __restrict__ h32, const int* __restrict__ cnt,
    const int* __restrict__ bucket, unsigned* __restrict__ G32)
{
  int gid = blockIdx.x*256 + threadIdx.x;
  int n = gid >> 7;                          // 2 rows per block
  int j = gid & 127;
  unsigned hv = h32[(size_t)n*128 + j];      // pad rows are zero
  float lo = bf2f((u16)(hv & 0xFFFFu));
  float hi = bf2f((u16)(hv >> 16));
  int c = (n < N_NODES) ? min(cnt[n], CAP) : 0;
  const int* bk = &bucket[(size_t)n*CAP];
  for (int k = 0; k < c; k++){
    int s = bk[k];
    unsigned v = h32[(size_t)s*128 + j];
    lo += bf2f((u16)(v & 0xFFFFu));
    hi += bf2f((u16)(v >> 16));
  }
  G32[(size_t)n*128 + j] = (unsigned)f2bf(lo) | ((unsigned)f2bf(hi) << 16);
}

// ---- overflow fallback (normally a no-op) -----------------------------------
__global__ void k_ovf_scatter(const unsigned* __restrict__ h32,
                              const int* __restrict__ ei,
                              const int* __restrict__ ovf,
                              const int* __restrict__ ovfcnt,
                              unsigned* __restrict__ G32){
  const long work = (long)(*ovfcnt) * 128;
  for (long i = (long)blockIdx.x*256 + threadIdx.x; i < work;
       i += (long)gridDim.x*256){
    int e = ovf[i >> 7];
    int j = (int)(i & 127);
    int s = ei[e];
    int d = ei[N_EDGES + e];
    unsigned sv = h32[(size_t)s*128 + j];
    float vlo = bf2f((u16)(sv & 0xFFFFu));
    float vhi = bf2f((u16)(sv >> 16));
    unsigned* addr = &G32[(size_t)d*128 + j];
    unsigned old = *addr;
    while (true){
      unsigned assumed = old;
      u16 nl = f2bf(bf2f((u16)(assumed & 0xFFFFu)) + vlo);
      u16 nh = f2bf(bf2f((u16)(assumed >> 16)) + vhi);
      unsigned nv = (unsigned)nl | ((unsigned)nh << 16);
      old = atomicCAS(addr, assumed, nv);
      if (old == assumed) break;
    }
  }
}

// ---- shared pieces for the fused MFMA kernels -------------------------------
// stage one 128x256 bf16 tile global->LDS, swizzled, fully coalesced (1KB/wave)
__device__ __forceinline__ void stage_tile(const u16* __restrict__ g,
                                           u16* __restrict__ tile,
                                           size_t rowBase, int tid){
  #pragma unroll
  for (int j=0;j<8;j++){
    int cid = j*512 + tid;               // 4096 16B chunks
    int r  = cid >> 5;
    int cb = (cid & 31) << 4;            // colByte
    uint4 v = *(const uint4*)((const char*)g + (((rowBase + r) << 9) + cb));
    *(uint4*)((char*)tile + swzb(r, cb)) = v;
  }
}

// B fragment (16 weight rows x 8 k) straight from global (L2-resident weights)
__device__ __forceinline__ short8 ldW(const void* W, long elemOff, bool f32){
  if (f32){
    const float* p = (const float*)W + elemOff;
    float4 a = *(const float4*)p;
    float4 b = *(const float4*)(p + 4);
    short8 r;
    r[0]=(short)f2bf(a.x); r[1]=(short)f2bf(a.y); r[2]=(short)f2bf(a.z); r[3]=(short)f2bf(a.w);
    r[4]=(short)f2bf(b.x); r[5]=(short)f2bf(b.y); r[6]=(short)f2bf(b.z); r[7]=(short)f2bf(b.w);
    return r;
  }
  return *(const short8*)((const u16*)W + elemOff);
}

// barrier-free K-loop: A from LDS tile(s), B from global. KT = 256 or 512.
template<int KT>
__device__ __forceinline__ void gate_gemm(
    f32x4 (&acc)[4][4], const u16* __restrict__ tA1, const u16* __restrict__ tA2,
    const void* __restrict__ Wv1, const void* __restrict__ Wv2,
    long wO1, long wO2, bool f32, int wr, int wc, int fr, int quad)
{
  constexpr int NH = KT/256;
  #pragma unroll
  for (int h2=0; h2<NH; h2++){
    const u16* tA  = h2 ? tA2 : tA1;
    const void* Wv = h2 ? Wv2 : Wv1;
    const long  wO = h2 ? wO2 : wO1;
    #pragma unroll
    for (int kk=0; kk<256; kk+=32){
      short8 af[4], bf[4];
      #pragma unroll
      for (int mi=0;mi<4;mi++)
        af[mi] = *(const short8*)((const char*)tA + swzb(wr + mi*16 + fr, kk*2 + quad*16));
      #pragma unroll
      for (int ni=0;ni<4;ni++)
        bf[ni] = ldW(Wv, wO + (long)(wc + ni*16 + fr)*256 + kk + quad*8, f32);
      #pragma unroll
      for (int mi=0;mi<4;mi++)
        #pragma unroll
        for (int ni=0;ni<4;ni++)
          acc[mi][ni] = __builtin_amdgcn_mfma_f32_16x16x32_bf16(af[mi], bf[ni], acc[mi][ni], 0, 0, 0);
    }
  }
}

#define ZERO_ACC(a) { f32x4 _z = {0.f,0.f,0.f,0.f}; \
  _Pragma("unroll") for (int _i=0;_i<4;_i++) \
  _Pragma("unroll") for (int _j=0;_j<4;_j++) a[_i][_j] = _z; }

// ---- fused GIN MLP: G = relu(relu(G@W1^T+b1)@W2^T+b2), + BN partial sums ----
// 512 threads, 8 waves (2 row x 4 col groups of 64x64), 128 rows x 256 cols.
__global__ __launch_bounds__(512, 2) void k_mlp(
    u16* __restrict__ Gp,
    const void* __restrict__ w1, const void* __restrict__ b1,
    const void* __restrict__ w2, const void* __restrict__ b2,
    long wO, long bO, float* __restrict__ bns, const int* __restrict__ dflag)
{
  const bool f32 = (*dflag != 0);
  __shared__ u16 Ag[128*256];
  __shared__ u16 At[128*256];
  const int tid = threadIdx.x;
  const size_t rowBase = (size_t)blockIdx.x * 128;
  const int lane = tid & 63, wave = tid >> 6;
  const int wr = (wave >> 2) * 64, wc = (wave & 3) * 64;
  const int fr = lane & 15, quad = lane >> 4;

  stage_tile(Gp, Ag, rowBase, tid);
  __syncthreads();

  f32x4 acc[4][4];
  ZERO_ACC(acc);
  gate_gemm<256>(acc, Ag, nullptr, w1, nullptr, wO, 0, f32, wr, wc, fr, quad);

  // t = relu(acc + b1) -> LDS (swizzled, same layout as Ag)
  #pragma unroll
  for (int ni=0;ni<4;ni++){
    const int col = wc + ni*16 + fr;
    const float bv = ldext(b1, bO + col, f32);
    #pragma unroll
    for (int mi=0;mi<4;mi++)
      #pragma unroll
      for (int r4=0;r4<4;r4++){
        const int row = wr + mi*16 + quad*4 + r4;
        float v = fmaxf(acc[mi][ni][r4] + bv, 0.f);
        *(u16*)((char*)At + swzb(row, col*2)) = f2bf(v);
      }
  }
  __syncthreads();

  ZERO_ACC(acc);
  gate_gemm<256>(acc, At, nullptr, w2, nullptr, wO, 0, f32, wr, wc, fr, quad);

  // g = relu(acc + b2) -> global, plus per-column BN partial sums
  #pragma unroll
  for (int ni=0;ni<4;ni++){
    const int col = wc + ni*16 + fr;
    const float bv = ldext(b2, bO + col, f32);
    float s1 = 0.f, s2 = 0.f;
    #pragma unroll
    for (int mi=0;mi<4;mi++)
      #pragma unroll
      for (int r4=0;r4<4;r4++){
        const int row = wr + mi*16 + quad*4 + r4;
        const size_t grow = rowBase + row;
        float v = fmaxf(acc[mi][ni][r4] + bv, 0.f);
        Gp[grow*256 + col] = f2bf(v);
        if (grow < N_NODES){ s1 += v; s2 += v*v; }
      }
    s1 += __shfl_xor(s1, 16); s1 += __shfl_xor(s1, 32);   // reduce over quad
    s2 += __shfl_xor(s2, 16); s2 += __shfl_xor(s2, 32);
    if (quad == 0){
      unsafeAtomicAdd(&bns[col],       s1);
      unsafeAtomicAdd(&bns[256 + col], s2);
    }
  }
}

// ---- fused GRU: all 4 gate GEMMs, zero K-loop barriers ----------------------
// out = (1-z)*tanh(in + r*hn) + z*h, gates from LDS-resident G,h tiles.
__global__ __launch_bounds__(512, 2) void k_gru(
    const u16* __restrict__ Gp, const u16* __restrict__ hp,
    const void* __restrict__ wih, const void* __restrict__ whh,
    const void* __restrict__ bih, const void* __restrict__ bhh,
    long wo, long bo, u16* __restrict__ outp, const int* __restrict__ dflag)
{
  const bool f32 = (*dflag != 0);
  __shared__ u16 Ag[128*256];
  __shared__ u16 Ah[128*256];
  const int tid = threadIdx.x;
  const size_t rowBase = (size_t)blockIdx.x * 128;
  const int lane = tid & 63, wave = tid >> 6;
  const int wr = (wave >> 2) * 64, wc = (wave & 3) * 64;
  const int fr = lane & 15, quad = lane >> 4;

  stage_tile(Gp, Ag, rowBase, tid);
  stage_tile(hp, Ah, rowBase, tid);
  __syncthreads();

  // stage 1: hn = h@Whn^T + bhh_n
  f32x4 hn[4][4];
  ZERO_ACC(hn);
  gate_gemm<256>(hn, Ah, nullptr, whh, nullptr, wo + 512*256, 0, f32, wr, wc, fr, quad);
  #pragma unroll
  for (int ni=0;ni<4;ni++){
    const float bv = ldext(bhh, bo + 512 + wc + ni*16 + fr, f32);
    #pragma unroll
    for (int mi=0;mi<4;mi++)
      #pragma unroll
      for (int r4=0;r4<4;r4++) hn[mi][ni][r4] += bv;
  }

  // stage 2: r = sigm([g|h]@[Wir|Whr]^T + bir + bhr); hn <- r*hn
  f32x4 acc[4][4];
  ZERO_ACC(acc);
  gate_gemm<512>(acc, Ag, Ah, wih, whh, wo, wo, f32, wr, wc, fr, quad);
  #pragma unroll
  for (int ni=0;ni<4;ni++){
    const int col = wc + ni*16 + fr;
    const float bv = ldext(bih, bo + col, f32) + ldext(bhh, bo + col, f32);
    #pragma unroll
    for (int mi=0;mi<4;mi++)
      #pragma unroll
      for (int r4=0;r4<4;r4++)
        hn[mi][ni][r4] *= sigm(acc[mi][ni][r4] + bv);
  }

  // stage 3: n = tanh(g@Win^T + bin + r*hn); hn <- n
  ZERO_ACC(acc);
  gate_gemm<256>(acc, Ag, nullptr, wih, nullptr, wo + 512*256, 0, f32, wr, wc, fr, quad);
  #pragma unroll
  for (int ni=0;ni<4;ni++){
    const float bv = ldext(bih, bo + 512 + wc + ni*16 + fr, f32);
    #pragma unroll
    for (int mi=0;mi<4;mi++)
      #pragma unroll
      for (int r4=0;r4<4;r4++)
        hn[mi][ni][r4] = tanhf(acc[mi][ni][r4] + bv + hn[mi][ni][r4]);
  }

  // stage 4: z = sigm([g|h]@[Wiz|Whz]^T + biz + bhz); out = (1-z)*n + z*h
  ZERO_ACC(acc);
  gate_gemm<512>(acc, Ag, Ah, wih, whh, wo + 256*256, wo + 256*256, f32, wr, wc, fr, quad);
  #pragma unroll
  for (int ni=0;ni<4;ni++){
    const int col = wc + ni*16 + fr;
    const float bv = ldext(bih, bo + 256 + col, f32) + ldext(bhh, bo + 256 + col, f32);
    #pragma unroll
    for (int mi=0;mi<4;mi++)
      #pragma unroll
      for (int r4=0;r4<4;r4++){
        const int row = wr + mi*16 + quad*4 + r4;
        const float z = sigm(acc[mi][ni][r4] + bv);
        const float hval = bf2f(*(const u16*)((const char*)Ah + swzb(row, col*2)));
        const float v = (1.f - z)*hn[mi][ni][r4] + z*hval;
        outp[(rowBase + row)*256 + col] = f2bf(v);
      }
  }
}

// ---- BatchNorm apply (stats come fused from k_mlp) --------------------------
__global__ void k_bn_apply(u16* __restrict__ G,
                           const void* __restrict__ gam, const void* __restrict__ bet,
                           long gO, const float* __restrict__ sums,
                           const int* __restrict__ dflag){
  const bool f32 = (*dflag != 0);
  int i = blockIdx.x*256 + threadIdx.x;
  size_t base = (size_t)i*4;
  int col = (int)(base & 255);
  ushort4 v = *(const ushort4*)&G[base];
  float vv[4] = {bf2f(v.x), bf2f(v.y), bf2f(v.z), bf2f(v.w)};
  u16 o[4];
  #pragma unroll
  for (int j=0;j<4;j++){
    float mu  = sums[col+j] * (1.f/N_NODES);
    float var = sums[256+col+j] * (1.f/N_NODES) - mu*mu;
    float sc  = ldext(gam, gO+col+j, f32) * rsqrtf(fmaxf(var, 0.f) + LN_EPS);
    o[j] = f2bf((vv[j]-mu)*sc + ldext(bet, gO+col+j, f32));
  }
  *(ushort4*)&G[base] = make_ushort4(o[0], o[1], o[2], o[3]);
}

// ---- LayerNorm(hnew) + h/m/e update; layer2: m/e maxima via reduced atomics -
__global__ __launch_bounds__(256) void k_fin(
    const u16* __restrict__ hn, u16* __restrict__ h,
    u16* __restrict__ mb, u16* __restrict__ eb,
    const void* __restrict__ lng, const void* __restrict__ lnb,
    const int* __restrict__ batch, unsigned* __restrict__ outenc,
    int layer, int r0, const int* __restrict__ dflag)
{
  const bool f32 = (*dflag != 0);
  const int wave = threadIdx.x >> 6, lane = threadIdx.x & 63;
  const int n  = blockIdx.x*4 + wave;        // local row
  const int d0 = lane*4;
  const size_t rb = (size_t)n*256 + d0;
  float hv[4], mv[4], ev[4];
  ld4bf(&hn[rb], hv);
  if (layer != 0){
    ld4bf(&mb[rb], mv);
    ld4bf(&eb[rb], ev);
  }

  float s1 = 0.f, s2 = 0.f;
  #pragma unroll
  for (int j=0;j<4;j++){ s1 += hv[j]; s2 += hv[j]*hv[j]; }
  #pragma unroll
  for (int off=1; off<64; off<<=1){
    s1 += __shfl_xor(s1, off);
    s2 += __shfl_xor(s2, off);
  }
  const float mu   = s1 * (1.f/256.f);
  const float var  = s2 * (1.f/256.f) - mu*mu;
  const float rstd = rsqrtf(fmaxf(var, 0.f) + LN_EPS);

  float hl[4];
  #pragma unroll
  for (int j=0;j<4;j++){
    hl[j] = (hv[j]-mu)*rstd*ldext(lng, d0+j, f32) + ldext(lnb, d0+j, f32);
    if (layer == 0){ mv[j] = hl[j];  ev[j] = hl[j]; }
    else           { mv[j] *= hl[j]; ev[j] += hl[j]; }
  }
  *(ushort4*)&h[rb]  = make_ushort4(f2bf(hl[0]), f2bf(hl[1]), f2bf(hl[2]), f2bf(hl[3]));
  if (layer != 2){                            // m/e planes dead after layer 2
    *(ushort4*)&mb[rb] = make_ushort4(f2bf(mv[0]), f2bf(mv[1]), f2bf(mv[2]), f2bf(mv[3]));
    *(ushort4*)&eb[rb] = make_ushort4(f2bf(ev[0]), f2bf(ev[1]), f2bf(ev[2]), f2bf(ev[3]));
  }

  if (layer == 2){
    __shared__ float redm[1024], rede[1024];
    __shared__ int bgs[4];
    const int ng = r0 + n;
    if (lane == 0) bgs[wave] = (ng < N_NODES) ? batch[ng] : -1;
    #pragma unroll
    for (int j=0;j<4;j++){ redm[wave*256 + d0 + j] = mv[j]; rede[wave*256 + d0 + j] = ev[j]; }
    __syncthreads();
    const bool uniform = (bgs[0] >= 0) && bgs[0]==bgs[1] && bgs[1]==bgs[2] && bgs[2]==bgs[3];
    if (uniform){
      const int c = threadIdx.x;              // 256 threads = 256 cols
      float mm = fmaxf(fmaxf(redm[c], redm[256+c]), fmaxf(redm[512+c], redm[768+c]));
      float me = fmaxf(fmaxf(rede[c], rede[256+c]), fmaxf(rede[512+c], rede[768+c]));
      unsigned* ob = &outenc[(size_t)bgs[0]*512];
      atomicMax(&ob[c],       enc_f(mm));
      atomicMax(&ob[256 + c], enc_f(me));
    } else {
      const int bg = (ng < N_NODES) ? batch[ng] : -1;
      if (bg >= 0){
        unsigned* ob = &outenc[(size_t)bg*512 + d0];
        atomicMax(&ob[0], enc_f(mv[0])); atomicMax(&ob[1], enc_f(mv[1]));
        atomicMax(&ob[2], enc_f(mv[2])); atomicMax(&ob[3], enc_f(mv[3]));
        atomicMax(&ob[256+0], enc_f(ev[0])); atomicMax(&ob[256+1], enc_f(ev[1]));
        atomicMax(&ob[256+2], enc_f(ev[2])); atomicMax(&ob[256+3], enc_f(ev[3]));
      }
    }
  }
}

// ---- atomic-free segment max over sorted batch: h plane -> out slice --------
__global__ __launch_bounds__(256) void k_segmax(
    const u16* __restrict__ plane, void* __restrict__ out, long slice,
    const int* __restrict__ batch, const int* __restrict__ dflag)
{
  const bool f32 = (*dflag != 0);
  const int g = blockIdx.x*4 + (threadIdx.x >> 6);
  const int lane = threadIdx.x & 63;
  int lo = 0, hi = N_NODES;
  while (lo < hi){ int mid = (lo + hi) >> 1; if (batch[mid] < g) lo = mid + 1; else hi = mid; }
  const int s = lo;
  hi = N_NODES;
  while (lo < hi){ int mid = (lo + hi) >> 1; if (batch[mid] < g + 1) lo = mid + 1; else hi = mid; }
  const int epos = lo;

  const float NINF = __uint_as_float(0xFF800000u);
  float a0=NINF, a1=NINF, a2=NINF, a3=NINF;
  for (int r = s; r < epos; r++){
    ushort4 v = *(const ushort4*)&plane[(size_t)r*256 + lane*4];
    a0 = fmaxf(a0, bf2f(v.x)); a1 = fmaxf(a1, bf2f(v.y));
    a2 = fmaxf(a2, bf2f(v.z)); a3 = fmaxf(a3, bf2f(v.w));
  }
  const long ob = (long)g*1280 + slice + lane*4;
  if (f32){
    float* o = (float*)out + ob;
    o[0]=a0; o[1]=a1; o[2]=a2; o[3]=a3;
  } else {
    *(ushort4*)((u16*)out + ob) = make_ushort4(f2bf(a0), f2bf(a1), f2bf(a2), f2bf(a3));
  }
}

// decode m/e maxima: oenc[g*512 + c] -> out[g*1280 + 768 + c]
__global__ void k_decode_me(const unsigned* __restrict__ enc, void* __restrict__ out,
                            const int* __restrict__ dflag){
  const bool f32 = (*dflag != 0);
  int i = blockIdx.x*256 + threadIdx.x;      // 4096*512
  int g = i >> 9, c = i & 511;
  unsigned u = enc[i];
  float f = (u == 0u) ? __uint_as_float(0xFF800000u) : dec_f(u);  // empty -> -inf
  long o = (long)g*1280 + 768 + c;
  if (f32) ((float*)out)[o] = f;
  else     ((u16*)out)[o]   = f2bf(f);
}

// ---- launcher ---------------------------------------------------------------
extern "C" void kernel_launch(void* const* d_in, const int* in_sizes, int n_in,
                              void* d_out, int out_size, void* d_ws, size_t ws_size,
                              hipStream_t stream)
{
  const void* x   = d_in[0];
  const void* l1w = d_in[1];  const void* l1b = d_in[2];
  const void* l2w = d_in[3];  const void* l2b = d_in[4];
  const void* bng = d_in[5];  const void* bnb = d_in[6];
  const void* wih = d_in[7];  const void* whh = d_in[8];
  const void* bih = d_in[9];  const void* bhh = d_in[10];
  const void* lng = d_in[11]; const void* lnb = d_in[12];
  const int* ei    = (const int*)d_in[13];
  const int* batch = (const int*)d_in[14];
  (void)in_sizes; (void)n_in; (void)out_size;

  const size_t PL = S_EL * 2;            // bf16 plane bytes (51.25 MB)
  char* p = (char*)d_ws; size_t off = 0;
  auto take = [&](size_t b){ void* q = p + off; off += (b + 255) & ~(size_t)255; return q; };
  u16*      h    = (u16*)take(PL);
  u16*      m    = (u16*)take(PL);
  u16*      e    = (u16*)take(PL);
  u16*      G    = (u16*)take(PL);       // agg -> g0 -> g
  unsigned* oenc = (unsigned*)take(OENC_B);
  float*    bns  = (float*)take(512*4);
  int*      dflg = (int*)take(256);
  int*      cnt  = (int*)take((size_t)N_NODES*4);
  int*      bkt  = (int*)take((size_t)N_NODES*CAP*4);   // 12.8 MB
  int*      ovf  = (int*)take((size_t)N_EDGES*4);       // worst-case overflow list
  int*      ovfc = (int*)take(256);
  // hnew chunk scratch sized from the actual remaining workspace
  const size_t TILE_B = 128*256*2;       // one 128-row bf16 tile (64 KB)
  size_t rem = (ws_size > off + TILE_B) ? (ws_size - off) : TILE_B;
  int CT = (int)(rem / TILE_B);          // tiles per chunk
  if (CT < 1) CT = 1;
  if (CT > N_TILES) CT = N_TILES;
  u16* S2 = (u16*)take((size_t)CT*TILE_B);

  k_detect<<<1, 64, 0, stream>>>((const unsigned*)x, dflg);
  hipMemsetAsync(oenc, 0, OENC_B, stream);
  hipMemsetAsync(cnt, 0, (size_t)N_NODES*4, stream);
  hipMemsetAsync(ovfc, 0, 4, stream);
  k_h_init <<<S_EL/8/256, 256, 0, stream>>>(x, h, dflg);
  k_bucket_build<<<(N_EDGES + 255)/256, 256, 0, stream>>>(ei, cnt, bkt, ovf, ovfc);

  for (int l = 0; l < 3; l++){
    const long wo = (long)l*768*256;     // per-layer GRU weight element offset
    const long bo = (long)l*768;
    hipMemsetAsync(bns, 0, 512*4, stream);
    k_gather<<<(M_PAD*128)/256, 256, 0, stream>>>((const unsigned*)h, cnt, bkt, (unsigned*)G);
    k_ovf_scatter<<<512, 256, 0, stream>>>((const unsigned*)h, ei, ovf, ovfc, (unsigned*)G);

    // fused MLP (lin1+relu+lin2+relu) in-place on G, with fused BN stats
    k_mlp<<<N_TILES, 512, 0, stream>>>(G, l1w, l1b, l2w, l2b,
                                       (long)l*65536, (long)l*256, bns, dflg);
    k_bn_apply<<<S_EL/4/256, 256, 0, stream>>>(G, bng, bnb, (long)l*256, bns, dflg);

    for (int t0 = 0; t0 < N_TILES; t0 += CT){
      const int ct = min(CT, N_TILES - t0);
      const size_t o2 = (size_t)t0*128*256;
      k_gru<<<ct, 512, 0, stream>>>(G + o2, h + o2, wih, whh, bih, bhh,
                                    wo, bo, S2, dflg);
      k_fin<<<ct*128/4, 256, 0, stream>>>(S2, h + o2, m + o2, e + o2,
                                          lng, lnb, batch, oenc, l, t0*128, dflg);
    }
    k_segmax<<<N_GRAPH/4, 256, 0, stream>>>(h, d_out, (long)l*256, batch, dflg);
  }
  k_decode_me<<<(N_GRAPH*512)/256, 256, 0, stream>>>(oenc, d_out, dflg);
}

// Round 3
// 2655.329 us; speedup vs baseline: 1.2316x; 1.2316x over previous
//
#include <hip/hip_runtime.h>

// HierarchicalGraphNet: N=100000 nodes, E=320000 edges, D=256, L=3, G=4096.
#define N_NODES 100000
#define N_EDGES 320000
#define N_GRAPH 4096
#define M_PAD   100096                   // N padded to multiple of 128
#define N_TILES 782                      // M_PAD / 128
#define LN_EPS  1e-5f
#define S_EL    ((size_t)M_PAD * 256)    // elements per full M x 256 plane
#define OENC_B  ((size_t)N_GRAPH * 512 * 4)   // m|e encoded maxima only
#define CAP     32                       // in-edge bucket capacity per node

typedef __attribute__((ext_vector_type(8))) short short8;   // 8 x bf16 MFMA operand
typedef __attribute__((ext_vector_type(4))) float f32x4;    // MFMA accumulator
typedef unsigned short u16;

__device__ __forceinline__ float bf2f(u16 u){
  return __uint_as_float(((unsigned)u) << 16);
}
__device__ __forceinline__ u16 f2bf(float f){   // RNE round
  unsigned u = __float_as_uint(f);
  return (u16)((u + 0x7FFFu + ((u >> 16) & 1u)) >> 16);
}
// external float tensor read: fp32 or bf16 per runtime flag
__device__ __forceinline__ float ldext(const void* p, long i, bool f32){
  return f32 ? ((const float*)p)[i] : bf2f(((const u16*)p)[i]);
}
// order-preserving float<->uint encoding for atomicMax-based segment_max
__device__ __forceinline__ unsigned enc_f(float f){
  unsigned u = __float_as_uint(f);
  return (u & 0x80000000u) ? ~u : (u | 0x80000000u);
}
__device__ __forceinline__ float dec_f(unsigned e){
  unsigned u = (e & 0x80000000u) ? (e & 0x7FFFFFFFu) : ~e;
  return __uint_as_float(u);
}
__device__ __forceinline__ float sigm(float x){ return 1.0f/(1.0f + __expf(-x)); }
__device__ __forceinline__ void ld4bf(const u16* p, float* o){
  ushort4 v = *(const ushort4*)p;
  o[0]=bf2f(v.x); o[1]=bf2f(v.y); o[2]=bf2f(v.z); o[3]=bf2f(v.w);
}

// swizzled byte offset inside one A-tile (rows x 256 bf16, row=512B)
// XOR row bits into byte-addr bits [4..6]: breaks row-strided ds_read_b128
// bank conflicts (G4), bijective per 8-row stripe.
__device__ __forceinline__ int swzb(int row, int colByte){
  return (row << 9) + (colByte ^ ((row & 7) << 4));
}

// ---- dtype detector ---------------------------------------------------------
__global__ void k_detect(const unsigned* __restrict__ x32, int* __restrict__ flag){
  unsigned u = x32[threadIdx.x];            // 64 threads
  int ef = (int)((u >> 23) & 0xFFu);
  int ok = (ef >= 64 && ef <= 190) ? 1 : 0;
  #pragma unroll
  for (int o=1; o<64; o<<=1) ok += __shfl_xor(ok, o);
  if (threadIdx.x == 0) *flag = (ok >= 32) ? 1 : 0;
}

// ---- weight pre-conversion to bf16 (runs once, removes f32 from hot loops) --
__global__ void k_wconv(const void* __restrict__ src, u16* __restrict__ dst,
                        const int* __restrict__ dflag){
  const bool f32 = (*dflag != 0);
  size_t base = ((size_t)blockIdx.x*256 + threadIdx.x)*8;
  if (f32){
    const float* s = (const float*)src + base;
    float4 a = *(const float4*)s;
    float4 b = *(const float4*)(s + 4);
    ushort4 lo = make_ushort4(f2bf(a.x),f2bf(a.y),f2bf(a.z),f2bf(a.w));
    ushort4 hi = make_ushort4(f2bf(b.x),f2bf(b.y),f2bf(b.z),f2bf(b.w));
    uint4 v;
    v.x = (unsigned)lo.x | ((unsigned)lo.y<<16);
    v.y = (unsigned)lo.z | ((unsigned)lo.w<<16);
    v.z = (unsigned)hi.x | ((unsigned)hi.y<<16);
    v.w = (unsigned)hi.z | ((unsigned)hi.w<<16);
    *(uint4*)&dst[base] = v;
  } else {
    *(uint4*)&dst[base] = *(const uint4*)((const u16*)src + base);
  }
}

// ---- init kernels -----------------------------------------------------------
__global__ void k_h_init(const void* __restrict__ x, u16* __restrict__ h,
                         const int* __restrict__ dflag){
  const bool f32 = (*dflag != 0);
  int i = blockIdx.x*256 + threadIdx.x;     // 8 elements per thread
  size_t base = (size_t)i*8;
  int n = (int)(base >> 8);
  uint4 v = make_uint4(0,0,0,0);
  if (n < N_NODES){
    if (f32){
      const float* xf = (const float*)x + base;
      float4 a = *(const float4*)xf;
      float4 b = *(const float4*)(xf + 4);
      ushort4 lo = make_ushort4(f2bf(a.x),f2bf(a.y),f2bf(a.z),f2bf(a.w));
      ushort4 hi = make_ushort4(f2bf(b.x),f2bf(b.y),f2bf(b.z),f2bf(b.w));
      v.x = (unsigned)lo.x | ((unsigned)lo.y<<16);
      v.y = (unsigned)lo.z | ((unsigned)lo.w<<16);
      v.z = (unsigned)hi.x | ((unsigned)hi.y<<16);
      v.w = (unsigned)hi.z | ((unsigned)hi.w<<16);
    } else {
      v = *(const uint4*)((const u16*)x + base);
    }
  }
  *(uint4*)&h[base] = v;
}

// ---- inverse-CSR bucket build (edges are static across layers) --------------
__global__ void k_bucket_build(const int* __restrict__ ei, int* __restrict__ cnt,
                               int* __restrict__ bucket, int* __restrict__ ovf,
                               int* __restrict__ ovfcnt){
  int e = blockIdx.x*256 + threadIdx.x;
  if (e >= N_EDGES) return;
  int s = ei[e];
  int d = ei[N_EDGES + e];
  int pos = atomicAdd(&cnt[d], 1);
  if (pos < CAP) bucket[(size_t)d*CAP + pos] = s;
  else { int o = atomicAdd(ovfcnt, 1); ovf[o] = e; }  // o < E always
}

// ---- atomic-free GIN aggregation: G[n] = h[n] + sum_{s->n} h[s] -------------
__global__ __launch_bounds__(256) void k_gather(
    const unsigned* __restrict__ h32, const int* __restrict__ cnt,
    const int* __restrict__ bucket, unsigned* __restrict__ G32)
{
  int gid = blockIdx.x*256 + threadIdx.x;
  int n = gid >> 7;                          // 2 rows per block
  int j = gid & 127;
  unsigned hv = h32[(size_t)n*128 + j];      // pad rows are zero
  float lo = bf2f((u16)(hv & 0xFFFFu));
  float hi = bf2f((u16)(hv >> 16));
  int c = (n < N_NODES) ? min(cnt[n], CAP) : 0;
  const int* bk = &bucket[(size_t)n*CAP];
  for (int k = 0; k < c; k++){
    int s = bk[k];
    unsigned v = h32[(size_t)s*128 + j];
    lo += bf2f((u16)(v & 0xFFFFu));
    hi += bf2f((u16)(v >> 16));
  }
  G32[(size_t)n*128 + j] = (unsigned)f2bf(lo) | ((unsigned)f2bf(hi) << 16);
}

// ---- overflow fallback (normally a no-op) -----------------------------------
__global__ void k_ovf_scatter(const unsigned* __restrict__ h32,
                              const int* __restrict__ ei,
                              const int* __restrict__ ovf,
                              const int* __restrict__ ovfcnt,
                              unsigned* __restrict__ G32){
  const long work = (long)(*ovfcnt) * 128;
  for (long i = (long)blockIdx.x*256 + threadIdx.x; i < work;
       i += (long)gridDim.x*256){
    int e = ovf[i >> 7];
    int j = (int)(i & 127);
    int s = ei[e];
    int d = ei[N_EDGES + e];
    unsigned sv = h32[(size_t)s*128 + j];
    float vlo = bf2f((u16)(sv & 0xFFFFu));
    float vhi = bf2f((u16)(sv >> 16));
    unsigned* addr = &G32[(size_t)d*128 + j];
    unsigned old = *addr;
    while (true){
      unsigned assumed = old;
      u16 nl = f2bf(bf2f((u16)(assumed & 0xFFFFu)) + vlo);
      u16 nh = f2bf(bf2f((u16)(assumed >> 16)) + vhi);
      unsigned nv = (unsigned)nl | ((unsigned)nh << 16);
      old = atomicCAS(addr, assumed, nv);
      if (old == assumed) break;
    }
  }
}

// ---- shared pieces for the fused MFMA kernels -------------------------------
// stage one 64x256 bf16 tile global->LDS, swizzled, fully coalesced
__device__ __forceinline__ void stage_tile64(const u16* __restrict__ g,
                                             u16* __restrict__ tile,
                                             size_t rowBase, int tid){
  #pragma unroll
  for (int j=0;j<4;j++){
    int cid = j*512 + tid;               // 2048 16B chunks
    int r  = cid >> 5;
    int cb = (cid & 31) << 4;            // colByte
    uint4 v = *(const uint4*)((const char*)g + (((rowBase + r) << 9) + cb));
    *(uint4*)((char*)tile + swzb(r, cb)) = v;
  }
}

// barrier-free K-loop: A from LDS tile(s), B (bf16 weights) from global/L2.
// Wave owns a 32x64 output tile: acc[2][4] fragments of 16x16.
template<int KT>
__device__ __forceinline__ void gate_gemm(
    f32x4 (&acc)[2][4], const u16* __restrict__ tA1, const u16* __restrict__ tA2,
    const u16* __restrict__ W1, const u16* __restrict__ W2,
    int wr, int wc, int fr, int quad)
{
  constexpr int NH = KT/256;
  #pragma unroll
  for (int h2=0; h2<NH; h2++){
    const u16* tA = h2 ? tA2 : tA1;
    const u16* Wv = h2 ? W2  : W1;
    #pragma unroll
    for (int kk=0; kk<256; kk+=32){
      short8 af[2], bf[4];
      #pragma unroll
      for (int mi=0;mi<2;mi++)
        af[mi] = *(const short8*)((const char*)tA + swzb(wr + mi*16 + fr, kk*2 + quad*16));
      #pragma unroll
      for (int ni=0;ni<4;ni++)
        bf[ni] = *(const short8*)&Wv[(size_t)(wc + ni*16 + fr)*256 + kk + quad*8];
      #pragma unroll
      for (int mi=0;mi<2;mi++)
        #pragma unroll
        for (int ni=0;ni<4;ni++)
          acc[mi][ni] = __builtin_amdgcn_mfma_f32_16x16x32_bf16(af[mi], bf[ni], acc[mi][ni], 0, 0, 0);
    }
  }
}

#define ZERO_ACC2(a) { f32x4 _z = {0.f,0.f,0.f,0.f}; \
  _Pragma("unroll") for (int _i=0;_i<2;_i++) \
  _Pragma("unroll") for (int _j=0;_j<4;_j++) a[_i][_j] = _z; }

// ---- fused GIN MLP: G = relu(relu(G@W1^T+b1)@W2^T+b2), + BN partial sums ----
// 512 threads, 8 waves (2 row x 4 col groups), block = 64 rows x 256 cols.
__global__ __launch_bounds__(512, 4) void k_mlp(
    u16* __restrict__ Gp,
    const u16* __restrict__ w1, const void* __restrict__ b1,
    const u16* __restrict__ w2, const void* __restrict__ b2,
    long bO, float* __restrict__ bns, const int* __restrict__ dflag)
{
  const bool f32 = (*dflag != 0);
  __shared__ u16 Ag[64*256];
  __shared__ u16 At[64*256];
  const int tid = threadIdx.x;
  const size_t rowBase = (size_t)blockIdx.x * 64;
  const int lane = tid & 63, wave = tid >> 6;
  const int wr = (wave >> 2) * 32, wc = (wave & 3) * 64;
  const int fr = lane & 15, quad = lane >> 4;

  stage_tile64(Gp, Ag, rowBase, tid);
  __syncthreads();

  f32x4 acc[2][4];
  ZERO_ACC2(acc);
  gate_gemm<256>(acc, Ag, nullptr, w1, nullptr, wr, wc, fr, quad);

  // t = relu(acc + b1) -> LDS (swizzled, same layout as Ag)
  #pragma unroll
  for (int ni=0;ni<4;ni++){
    const int col = wc + ni*16 + fr;
    const float bv = ldext(b1, bO + col, f32);
    #pragma unroll
    for (int mi=0;mi<2;mi++)
      #pragma unroll
      for (int r4=0;r4<4;r4++){
        const int row = wr + mi*16 + quad*4 + r4;
        float v = fmaxf(acc[mi][ni][r4] + bv, 0.f);
        *(u16*)((char*)At + swzb(row, col*2)) = f2bf(v);
      }
  }
  __syncthreads();

  ZERO_ACC2(acc);
  gate_gemm<256>(acc, At, nullptr, w2, nullptr, wr, wc, fr, quad);

  // g = relu(acc + b2) -> global, plus per-column BN partial sums
  #pragma unroll
  for (int ni=0;ni<4;ni++){
    const int col = wc + ni*16 + fr;
    const float bv = ldext(b2, bO + col, f32);
    float s1 = 0.f, s2 = 0.f;
    #pragma unroll
    for (int mi=0;mi<2;mi++)
      #pragma unroll
      for (int r4=0;r4<4;r4++){
        const int row = wr + mi*16 + quad*4 + r4;
        const size_t grow = rowBase + row;
        float v = fmaxf(acc[mi][ni][r4] + bv, 0.f);
        Gp[grow*256 + col] = f2bf(v);
        if (grow < N_NODES){ s1 += v; s2 += v*v; }
      }
    s1 += __shfl_xor(s1, 16); s1 += __shfl_xor(s1, 32);   // reduce over quad
    s2 += __shfl_xor(s2, 16); s2 += __shfl_xor(s2, 32);
    if (quad == 0){
      unsafeAtomicAdd(&bns[col],       s1);
      unsafeAtomicAdd(&bns[256 + col], s2);
    }
  }
}

// ---- fused GRU: all 4 gate GEMMs, zero K-loop barriers ----------------------
// out = (1-z)*tanh(in + r*hn) + z*h; block = 64 rows, wave = 32x64 outputs.
__global__ __launch_bounds__(512, 4) void k_gru(
    const u16* __restrict__ Gp, const u16* __restrict__ hp,
    const u16* __restrict__ wihl, const u16* __restrict__ whhl,
    const void* __restrict__ bih, const void* __restrict__ bhh,
    long bo, u16* __restrict__ outp, const int* __restrict__ dflag)
{
  const bool f32 = (*dflag != 0);
  __shared__ u16 Ag[64*256];
  __shared__ u16 Ah[64*256];
  const int tid = threadIdx.x;
  const size_t rowBase = (size_t)blockIdx.x * 64;
  const int lane = tid & 63, wave = tid >> 6;
  const int wr = (wave >> 2) * 32, wc = (wave & 3) * 64;
  const int fr = lane & 15, quad = lane >> 4;

  stage_tile64(Gp, Ag, rowBase, tid);
  stage_tile64(hp, Ah, rowBase, tid);
  __syncthreads();

  // stage 1: hn = h@Whn^T + bhh_n
  f32x4 hn[2][4];
  ZERO_ACC2(hn);
  gate_gemm<256>(hn, Ah, nullptr, whhl + 512*256, nullptr, wr, wc, fr, quad);
  #pragma unroll
  for (int ni=0;ni<4;ni++){
    const float bv = ldext(bhh, bo + 512 + wc + ni*16 + fr, f32);
    #pragma unroll
    for (int mi=0;mi<2;mi++)
      #pragma unroll
      for (int r4=0;r4<4;r4++) hn[mi][ni][r4] += bv;
  }

  // stage 2: r = sigm([g|h]@[Wir|Whr]^T + bir + bhr); hn <- r*hn
  f32x4 acc[2][4];
  ZERO_ACC2(acc);
  gate_gemm<512>(acc, Ag, Ah, wihl, whhl, wr, wc, fr, quad);
  #pragma unroll
  for (int ni=0;ni<4;ni++){
    const int col = wc + ni*16 + fr;
    const float bv = ldext(bih, bo + col, f32) + ldext(bhh, bo + col, f32);
    #pragma unroll
    for (int mi=0;mi<2;mi++)
      #pragma unroll
      for (int r4=0;r4<4;r4++)
        hn[mi][ni][r4] *= sigm(acc[mi][ni][r4] + bv);
  }

  // stage 3: n = tanh(g@Win^T + bin + r*hn); hn <- n
  ZERO_ACC2(acc);
  gate_gemm<256>(acc, Ag, nullptr, wihl + 512*256, nullptr, wr, wc, fr, quad);
  #pragma unroll
  for (int ni=0;ni<4;ni++){
    const float bv = ldext(bih, bo + 512 + wc + ni*16 + fr, f32);
    #pragma unroll
    for (int mi=0;mi<2;mi++)
      #pragma unroll
      for (int r4=0;r4<4;r4++)
        hn[mi][ni][r4] = tanhf(acc[mi][ni][r4] + bv + hn[mi][ni][r4]);
  }

  // stage 4: z = sigm([g|h]@[Wiz|Whz]^T + biz + bhz); out = (1-z)*n + z*h
  ZERO_ACC2(acc);
  gate_gemm<512>(acc, Ag, Ah, wihl + 256*256, whhl + 256*256, wr, wc, fr, quad);
  #pragma unroll
  for (int ni=0;ni<4;ni++){
    const int col = wc + ni*16 + fr;
    const float bv = ldext(bih, bo + 256 + col, f32) + ldext(bhh, bo + 256 + col, f32);
    #pragma unroll
    for (int mi=0;mi<2;mi++)
      #pragma unroll
      for (int r4=0;r4<4;r4++){
        const int row = wr + mi*16 + quad*4 + r4;
        const float z = sigm(acc[mi][ni][r4] + bv);
        const float hval = bf2f(*(const u16*)((const char*)Ah + swzb(row, col*2)));
        const float v = (1.f - z)*hn[mi][ni][r4] + z*hval;
        outp[(rowBase + row)*256 + col] = f2bf(v);
      }
  }
}

// ---- BatchNorm apply (stats come fused from k_mlp) --------------------------
__global__ void k_bn_apply(u16* __restrict__ G,
                           const void* __restrict__ gam, const void* __restrict__ bet,
                           long gO, const float* __restrict__ sums,
                           const int* __restrict__ dflag){
  const bool f32 = (*dflag != 0);
  int i = blockIdx.x*256 + threadIdx.x;
  size_t base = (size_t)i*4;
  int col = (int)(base & 255);
  ushort4 v = *(const ushort4*)&G[base];
  float vv[4] = {bf2f(v.x), bf2f(v.y), bf2f(v.z), bf2f(v.w)};
  u16 o[4];
  #pragma unroll
  for (int j=0;j<4;j++){
    float mu  = sums[col+j] * (1.f/N_NODES);
    float var = sums[256+col+j] * (1.f/N_NODES) - mu*mu;
    float sc  = ldext(gam, gO+col+j, f32) * rsqrtf(fmaxf(var, 0.f) + LN_EPS);
    o[j] = f2bf((vv[j]-mu)*sc + ldext(bet, gO+col+j, f32));
  }
  *(ushort4*)&G[base] = make_ushort4(o[0], o[1], o[2], o[3]);
}

// ---- LayerNorm(hnew) + h/m/e update; layer2: m/e maxima via reduced atomics -
__global__ __launch_bounds__(256) void k_fin(
    const u16* __restrict__ hn, u16* __restrict__ h,
    u16* __restrict__ mb, u16* __restrict__ eb,
    const void* __restrict__ lng, const void* __restrict__ lnb,
    const int* __restrict__ batch, unsigned* __restrict__ outenc,
    int layer, int r0, const int* __restrict__ dflag)
{
  const bool f32 = (*dflag != 0);
  const int wave = threadIdx.x >> 6, lane = threadIdx.x & 63;
  const int n  = blockIdx.x*4 + wave;        // local row
  const int d0 = lane*4;
  const size_t rb = (size_t)n*256 + d0;
  float hv[4], mv[4], ev[4];
  ld4bf(&hn[rb], hv);
  if (layer != 0){
    ld4bf(&mb[rb], mv);
    ld4bf(&eb[rb], ev);
  }

  float s1 = 0.f, s2 = 0.f;
  #pragma unroll
  for (int j=0;j<4;j++){ s1 += hv[j]; s2 += hv[j]*hv[j]; }
  #pragma unroll
  for (int off=1; off<64; off<<=1){
    s1 += __shfl_xor(s1, off);
    s2 += __shfl_xor(s2, off);
  }
  const float mu   = s1 * (1.f/256.f);
  const float var  = s2 * (1.f/256.f) - mu*mu;
  const float rstd = rsqrtf(fmaxf(var, 0.f) + LN_EPS);

  float hl[4];
  #pragma unroll
  for (int j=0;j<4;j++){
    hl[j] = (hv[j]-mu)*rstd*ldext(lng, d0+j, f32) + ldext(lnb, d0+j, f32);
    if (layer == 0){ mv[j] = hl[j];  ev[j] = hl[j]; }
    else           { mv[j] *= hl[j]; ev[j] += hl[j]; }
  }
  *(ushort4*)&h[rb]  = make_ushort4(f2bf(hl[0]), f2bf(hl[1]), f2bf(hl[2]), f2bf(hl[3]));
  if (layer != 2){                            // m/e planes dead after layer 2
    *(ushort4*)&mb[rb] = make_ushort4(f2bf(mv[0]), f2bf(mv[1]), f2bf(mv[2]), f2bf(mv[3]));
    *(ushort4*)&eb[rb] = make_ushort4(f2bf(ev[0]), f2bf(ev[1]), f2bf(ev[2]), f2bf(ev[3]));
  }

  if (layer == 2){
    __shared__ float redm[1024], rede[1024];
    __shared__ int bgs[4];
    const int ng = r0 + n;
    if (lane == 0) bgs[wave] = (ng < N_NODES) ? batch[ng] : -1;
    #pragma unroll
    for (int j=0;j<4;j++){ redm[wave*256 + d0 + j] = mv[j]; rede[wave*256 + d0 + j] = ev[j]; }
    __syncthreads();
    const bool uniform = (bgs[0] >= 0) && bgs[0]==bgs[1] && bgs[1]==bgs[2] && bgs[2]==bgs[3];
    if (uniform){
      const int c = threadIdx.x;              // 256 threads = 256 cols
      float mm = fmaxf(fmaxf(redm[c], redm[256+c]), fmaxf(redm[512+c], redm[768+c]));
      float me = fmaxf(fmaxf(rede[c], rede[256+c]), fmaxf(rede[512+c], rede[768+c]));
      unsigned* ob = &outenc[(size_t)bgs[0]*512];
      atomicMax(&ob[c],       enc_f(mm));
      atomicMax(&ob[256 + c], enc_f(me));
    } else {
      const int bg = (ng < N_NODES) ? batch[ng] : -1;
      if (bg >= 0){
        unsigned* ob = &outenc[(size_t)bg*512 + d0];
        atomicMax(&ob[0], enc_f(mv[0])); atomicMax(&ob[1], enc_f(mv[1]));
        atomicMax(&ob[2], enc_f(mv[2])); atomicMax(&ob[3], enc_f(mv[3]));
        atomicMax(&ob[256+0], enc_f(ev[0])); atomicMax(&ob[256+1], enc_f(ev[1]));
        atomicMax(&ob[256+2], enc_f(ev[2])); atomicMax(&ob[256+3], enc_f(ev[3]));
      }
    }
  }
}

// ---- atomic-free segment max over sorted batch: h plane -> out slice --------
__global__ __launch_bounds__(256) void k_segmax(
    const u16* __restrict__ plane, void* __restrict__ out, long slice,
    const int* __restrict__ batch, const int* __restrict__ dflag)
{
  const bool f32 = (*dflag != 0);
  const int g = blockIdx.x*4 + (threadIdx.x >> 6);
  const int lane = threadIdx.x & 63;
  int lo = 0, hi = N_NODES;
  while (lo < hi){ int mid = (lo + hi) >> 1; if (batch[mid] < g) lo = mid + 1; else hi = mid; }
  const int s = lo;
  hi = N_NODES;
  while (lo < hi){ int mid = (lo + hi) >> 1; if (batch[mid] < g + 1) lo = mid + 1; else hi = mid; }
  const int epos = lo;

  const float NINF = __uint_as_float(0xFF800000u);
  float a0=NINF, a1=NINF, a2=NINF, a3=NINF;
  for (int r = s; r < epos; r++){
    ushort4 v = *(const ushort4*)&plane[(size_t)r*256 + lane*4];
    a0 = fmaxf(a0, bf2f(v.x)); a1 = fmaxf(a1, bf2f(v.y));
    a2 = fmaxf(a2, bf2f(v.z)); a3 = fmaxf(a3, bf2f(v.w));
  }
  const long ob = (long)g*1280 + slice + lane*4;
  if (f32){
    float* o = (float*)out + ob;
    o[0]=a0; o[1]=a1; o[2]=a2; o[3]=a3;
  } else {
    *(ushort4*)((u16*)out + ob) = make_ushort4(f2bf(a0), f2bf(a1), f2bf(a2), f2bf(a3));
  }
}

// decode m/e maxima: oenc[g*512 + c] -> out[g*1280 + 768 + c]
__global__ void k_decode_me(const unsigned* __restrict__ enc, void* __restrict__ out,
                            const int* __restrict__ dflag){
  const bool f32 = (*dflag != 0);
  int i = blockIdx.x*256 + threadIdx.x;      // 4096*512
  int g = i >> 9, c = i & 511;
  unsigned u = enc[i];
  float f = (u == 0u) ? __uint_as_float(0xFF800000u) : dec_f(u);  // empty -> -inf
  long o = (long)g*1280 + 768 + c;
  if (f32) ((float*)out)[o] = f;
  else     ((u16*)out)[o]   = f2bf(f);
}

// ---- launcher ---------------------------------------------------------------
extern "C" void kernel_launch(void* const* d_in, const int* in_sizes, int n_in,
                              void* d_out, int out_size, void* d_ws, size_t ws_size,
                              hipStream_t stream)
{
  const void* x   = d_in[0];
  const void* l1w = d_in[1];  const void* l1b = d_in[2];
  const void* l2w = d_in[3];  const void* l2b = d_in[4];
  const void* bng = d_in[5];  const void* bnb = d_in[6];
  const void* wih = d_in[7];  const void* whh = d_in[8];
  const void* bih = d_in[9];  const void* bhh = d_in[10];
  const void* lng = d_in[11]; const void* lnb = d_in[12];
  const int* ei    = (const int*)d_in[13];
  const int* batch = (const int*)d_in[14];
  (void)in_sizes; (void)n_in; (void)out_size;

  const size_t PL = S_EL * 2;            // bf16 plane bytes (51.25 MB)
  char* p = (char*)d_ws; size_t off = 0;
  auto take = [&](size_t b){ void* q = p + off; off += (b + 255) & ~(size_t)255; return q; };
  u16*      h    = (u16*)take(PL);
  u16*      m    = (u16*)take(PL);
  u16*      e    = (u16*)take(PL);
  u16*      G    = (u16*)take(PL);       // agg -> g0 -> g
  unsigned* oenc = (unsigned*)take(OENC_B);
  float*    bns  = (float*)take(512*4);
  int*      dflg = (int*)take(256);
  int*      cnt  = (int*)take((size_t)N_NODES*4);
  int*      bkt  = (int*)take((size_t)N_NODES*CAP*4);   // 12.8 MB
  int*      ovf  = (int*)take((size_t)N_EDGES*4);       // worst-case overflow list
  int*      ovfc = (int*)take(256);
  // bf16 weight copies (all layers): lin1|lin2: 3*64K, wih|whh: 3*192K elems
  u16*      wb1  = (u16*)take((size_t)3*65536*2);
  u16*      wb2  = (u16*)take((size_t)3*65536*2);
  u16*      wbih = (u16*)take((size_t)3*196608*2);
  u16*      wbhh = (u16*)take((size_t)3*196608*2);
  // hnew chunk scratch sized from the actual remaining workspace
  const size_t TILE_B = 128*256*2;       // one 128-row bf16 tile (64 KB)
  size_t rem = (ws_size > off + TILE_B) ? (ws_size - off) : TILE_B;
  int CT = (int)(rem / TILE_B);          // tiles per chunk
  if (CT < 1) CT = 1;
  if (CT > N_TILES) CT = N_TILES;
  u16* S2 = (u16*)take((size_t)CT*TILE_B);

  k_detect<<<1, 64, 0, stream>>>((const unsigned*)x, dflg);
  hipMemsetAsync(oenc, 0, OENC_B, stream);
  hipMemsetAsync(cnt, 0, (size_t)N_NODES*4, stream);
  hipMemsetAsync(ovfc, 0, 4, stream);
  k_h_init <<<S_EL/8/256, 256, 0, stream>>>(x, h, dflg);
  k_bucket_build<<<(N_EDGES + 255)/256, 256, 0, stream>>>(ei, cnt, bkt, ovf, ovfc);
  k_wconv<<< 96, 256, 0, stream>>>(l1w, wb1,  dflg);   // 3*65536/8/256
  k_wconv<<< 96, 256, 0, stream>>>(l2w, wb2,  dflg);
  k_wconv<<<288, 256, 0, stream>>>(wih, wbih, dflg);   // 3*196608/8/256
  k_wconv<<<288, 256, 0, stream>>>(whh, wbhh, dflg);

  for (int l = 0; l < 3; l++){
    const long bo = (long)l*768;
    hipMemsetAsync(bns, 0, 512*4, stream);
    k_gather<<<(M_PAD*128)/256, 256, 0, stream>>>((const unsigned*)h, cnt, bkt, (unsigned*)G);
    k_ovf_scatter<<<512, 256, 0, stream>>>((const unsigned*)h, ei, ovf, ovfc, (unsigned*)G);

    // fused MLP (lin1+relu+lin2+relu) in-place on G, with fused BN stats
    k_mlp<<<N_TILES*2, 512, 0, stream>>>(G, wb1 + (size_t)l*65536, l1b,
                                         wb2 + (size_t)l*65536, l2b,
                                         (long)l*256, bns, dflg);
    k_bn_apply<<<S_EL/4/256, 256, 0, stream>>>(G, bng, bnb, (long)l*256, bns, dflg);

    for (int t0 = 0; t0 < N_TILES; t0 += CT){
      const int ct = min(CT, N_TILES - t0);
      const size_t o2 = (size_t)t0*128*256;
      k_gru<<<ct*2, 512, 0, stream>>>(G + o2, h + o2,
                                      wbih + (size_t)l*196608, wbhh + (size_t)l*196608,
                                      bih, bhh, bo, S2, dflg);
      k_fin<<<ct*128/4, 256, 0, stream>>>(S2, h + o2, m + o2, e + o2,
                                          lng, lnb, batch, oenc, l, t0*128, dflg);
    }
    k_segmax<<<N_GRAPH/4, 256, 0, stream>>>(h, d_out, (long)l*256, batch, dflg);
  }
  k_decode_me<<<(N_GRAPH*512)/256, 256, 0, stream>>>(oenc, d_out, dflg);
}

// Round 4
// 2340.458 us; speedup vs baseline: 1.3973x; 1.1345x over previous
//
#include <hip/hip_runtime.h>

// HierarchicalGraphNet: N=100000 nodes, E=320000 edges, D=256, L=3, G=4096.
#define N_NODES 100000
#define N_EDGES 320000
#define N_GRAPH 4096
#define M_PAD   100096                   // N padded to multiple of 128
#define N_TILES 782                      // M_PAD / 128
#define LN_EPS  1e-5f
#define S_EL    ((size_t)M_PAD * 256)    // elements per full M x 256 plane
#define OENC_B  ((size_t)N_GRAPH * 512 * 4)   // m|e encoded maxima only
#define CAP     32                       // in-edge bucket capacity per node

typedef __attribute__((ext_vector_type(8))) short short8;   // 8 x bf16 MFMA operand
typedef __attribute__((ext_vector_type(4))) float f32x4;    // MFMA accumulator
typedef unsigned short u16;

__device__ __forceinline__ float bf2f(u16 u){
  return __uint_as_float(((unsigned)u) << 16);
}
__device__ __forceinline__ u16 f2bf(float f){   // RNE round
  unsigned u = __float_as_uint(f);
  return (u16)((u + 0x7FFFu + ((u >> 16) & 1u)) >> 16);
}
// external float tensor read: fp32 or bf16 per runtime flag
__device__ __forceinline__ float ldext(const void* p, long i, bool f32){
  return f32 ? ((const float*)p)[i] : bf2f(((const u16*)p)[i]);
}
// order-preserving float<->uint encoding for atomicMax-based segment_max
__device__ __forceinline__ unsigned enc_f(float f){
  unsigned u = __float_as_uint(f);
  return (u & 0x80000000u) ? ~u : (u | 0x80000000u);
}
__device__ __forceinline__ float dec_f(unsigned e){
  unsigned u = (e & 0x80000000u) ? (e & 0x7FFFFFFFu) : ~e;
  return __uint_as_float(u);
}
__device__ __forceinline__ float sigm(float x){ return 1.0f/(1.0f + __expf(-x)); }
__device__ __forceinline__ void ld4bf(const u16* p, float* o){
  ushort4 v = *(const ushort4*)p;
  o[0]=bf2f(v.x); o[1]=bf2f(v.y); o[2]=bf2f(v.z); o[3]=bf2f(v.w);
}

// swizzled byte offset inside one A-tile (rows x 256 bf16, row=512B)
// XOR row bits into byte-addr bits [4..6]: breaks row-strided ds_read_b128
// bank conflicts (G4), bijective per 8-row stripe.
__device__ __forceinline__ int swzb(int row, int colByte){
  return (row << 9) + (colByte ^ ((row & 7) << 4));
}

// ---- dtype detector ---------------------------------------------------------
__global__ void k_detect(const unsigned* __restrict__ x32, int* __restrict__ flag){
  unsigned u = x32[threadIdx.x];            // 64 threads
  int ef = (int)((u >> 23) & 0xFFu);
  int ok = (ef >= 64 && ef <= 190) ? 1 : 0;
  #pragma unroll
  for (int o=1; o<64; o<<=1) ok += __shfl_xor(ok, o);
  if (threadIdx.x == 0) *flag = (ok >= 32) ? 1 : 0;
}

// ---- weight pre-conversion to bf16 (runs once, removes f32 from hot loops) --
__global__ void k_wconv(const void* __restrict__ src, u16* __restrict__ dst,
                        const int* __restrict__ dflag){
  const bool f32 = (*dflag != 0);
  size_t base = ((size_t)blockIdx.x*256 + threadIdx.x)*8;
  if (f32){
    const float* s = (const float*)src + base;
    float4 a = *(const float4*)s;
    float4 b = *(const float4*)(s + 4);
    ushort4 lo = make_ushort4(f2bf(a.x),f2bf(a.y),f2bf(a.z),f2bf(a.w));
    ushort4 hi = make_ushort4(f2bf(b.x),f2bf(b.y),f2bf(b.z),f2bf(b.w));
    uint4 v;
    v.x = (unsigned)lo.x | ((unsigned)lo.y<<16);
    v.y = (unsigned)lo.z | ((unsigned)lo.w<<16);
    v.z = (unsigned)hi.x | ((unsigned)hi.y<<16);
    v.w = (unsigned)hi.z | ((unsigned)hi.w<<16);
    *(uint4*)&dst[base] = v;
  } else {
    *(uint4*)&dst[base] = *(const uint4*)((const u16*)src + base);
  }
}

// ---- init kernels -----------------------------------------------------------
__global__ void k_h_init(const void* __restrict__ x, u16* __restrict__ h,
                         const int* __restrict__ dflag){
  const bool f32 = (*dflag != 0);
  int i = blockIdx.x*256 + threadIdx.x;     // 8 elements per thread
  size_t base = (size_t)i*8;
  int n = (int)(base >> 8);
  uint4 v = make_uint4(0,0,0,0);
  if (n < N_NODES){
    if (f32){
      const float* xf = (const float*)x + base;
      float4 a = *(const float4*)xf;
      float4 b = *(const float4*)(xf + 4);
      ushort4 lo = make_ushort4(f2bf(a.x),f2bf(a.y),f2bf(a.z),f2bf(a.w));
      ushort4 hi = make_ushort4(f2bf(b.x),f2bf(b.y),f2bf(b.z),f2bf(b.w));
      v.x = (unsigned)lo.x | ((unsigned)lo.y<<16);
      v.y = (unsigned)lo.z | ((unsigned)lo.w<<16);
      v.z = (unsigned)hi.x | ((unsigned)hi.y<<16);
      v.w = (unsigned)hi.z | ((unsigned)hi.w<<16);
    } else {
      v = *(const uint4*)((const u16*)x + base);
    }
  }
  *(uint4*)&h[base] = v;
}

// ---- inverse-CSR bucket build (edges are static across layers) --------------
__global__ void k_bucket_build(const int* __restrict__ ei, int* __restrict__ cnt,
                               int* __restrict__ bucket, int* __restrict__ ovf,
                               int* __restrict__ ovfcnt){
  int e = blockIdx.x*256 + threadIdx.x;
  if (e >= N_EDGES) return;
  int s = ei[e];
  int d = ei[N_EDGES + e];
  int pos = atomicAdd(&cnt[d], 1);
  if (pos < CAP) bucket[(size_t)d*CAP + pos] = s;
  else { int o = atomicAdd(ovfcnt, 1); ovf[o] = e; }  // o < E always
}

// ---- atomic-free GIN aggregation: G[n] = h[n] + sum_{s->n} h[s] -------------
__global__ __launch_bounds__(256) void k_gather(
    const unsigned* __restrict__ h32, const int* __restrict__ cnt,
    const int* __restrict__ bucket, unsigned* __restrict__ G32)
{
  int gid = blockIdx.x*256 + threadIdx.x;
  int n = gid >> 7;                          // 2 rows per block
  int j = gid & 127;
  unsigned hv = h32[(size_t)n*128 + j];      // pad rows are zero
  float lo = bf2f((u16)(hv & 0xFFFFu));
  float hi = bf2f((u16)(hv >> 16));
  int c = (n < N_NODES) ? min(cnt[n], CAP) : 0;
  const int* bk = &bucket[(size_t)n*CAP];
  for (int k = 0; k < c; k++){
    int s = bk[k];
    unsigned v = h32[(size_t)s*128 + j];
    lo += bf2f((u16)(v & 0xFFFFu));
    hi += bf2f((u16)(v >> 16));
  }
  G32[(size_t)n*128 + j] = (unsigned)f2bf(lo) | ((unsigned)f2bf(hi) << 16);
}

// ---- overflow fallback (normally a no-op) -----------------------------------
__global__ void k_ovf_scatter(const unsigned* __restrict__ h32,
                              const int* __restrict__ ei,
                              const int* __restrict__ ovf,
                              const int* __restrict__ ovfcnt,
                              unsigned* __restrict__ G32){
  const long work = (long)(*ovfcnt) * 128;
  for (long i = (long)blockIdx.x*256 + threadIdx.x; i < work;
       i += (long)gridDim.x*256){
    int e = ovf[i >> 7];
    int j = (int)(i & 127);
    int s = ei[e];
    int d = ei[N_EDGES + e];
    unsigned sv = h32[(size_t)s*128 + j];
    float vlo = bf2f((u16)(sv & 0xFFFFu));
    float vhi = bf2f((u16)(sv >> 16));
    unsigned* addr = &G32[(size_t)d*128 + j];
    unsigned old = *addr;
    while (true){
      unsigned assumed = old;
      u16 nl = f2bf(bf2f((u16)(assumed & 0xFFFFu)) + vlo);
      u16 nh = f2bf(bf2f((u16)(assumed >> 16)) + vhi);
      unsigned nv = (unsigned)nl | ((unsigned)nh << 16);
      old = atomicCAS(addr, assumed, nv);
      if (old == assumed) break;
    }
  }
}

// ---- shared pieces for the fused MFMA kernels -------------------------------
// stage one 64x256 bf16 tile global->LDS, swizzled, fully coalesced
__device__ __forceinline__ void stage_tile64(const u16* __restrict__ g,
                                             u16* __restrict__ tile,
                                             size_t rowBase, int tid){
  #pragma unroll
  for (int j=0;j<4;j++){
    int cid = j*512 + tid;               // 2048 16B chunks
    int r  = cid >> 5;
    int cb = (cid & 31) << 4;            // colByte
    uint4 v = *(const uint4*)((const char*)g + (((rowBase + r) << 9) + cb));
    *(uint4*)((char*)tile + swzb(r, cb)) = v;
  }
}

// same, but applies per-column BatchNorm (ss[2c]=scale, ss[2c+1]=shift)
__device__ __forceinline__ void stage_tile64_bn(const u16* __restrict__ g,
                                                u16* __restrict__ tile,
                                                size_t rowBase, int tid,
                                                const float* __restrict__ ss){
  #pragma unroll
  for (int j=0;j<4;j++){
    int cid = j*512 + tid;
    int r  = cid >> 5;
    int cb = (cid & 31) << 4;            // colByte; bf16 col0 = cb/2
    uint4 v = *(const uint4*)((const char*)g + (((rowBase + r) << 9) + cb));
    unsigned vv[4] = {v.x, v.y, v.z, v.w};
    uint4 o;
    unsigned* op = (unsigned*)&o;
    #pragma unroll
    for (int q=0;q<4;q++){
      float4 s2 = *(const float4*)&ss[cb + q*4];   // sc0,sh0,sc1,sh1
      float x0 = bf2f((u16)(vv[q] & 0xFFFFu))*s2.x + s2.y;
      float x1 = bf2f((u16)(vv[q] >> 16))    *s2.z + s2.w;
      op[q] = (unsigned)f2bf(x0) | ((unsigned)f2bf(x1) << 16);
    }
    *(uint4*)((char*)tile + swzb(r, cb)) = o;
  }
}

// barrier-free K-loop: A from LDS tile(s), B (bf16 weights) from global/L2.
// Wave owns a 32x64 output tile: acc[2][4] fragments of 16x16.
template<int KT>
__device__ __forceinline__ void gate_gemm(
    f32x4 (&acc)[2][4], const u16* __restrict__ tA1, const u16* __restrict__ tA2,
    const u16* __restrict__ W1, const u16* __restrict__ W2,
    int wr, int wc, int fr, int quad)
{
  constexpr int NH = KT/256;
  #pragma unroll
  for (int h2=0; h2<NH; h2++){
    const u16* tA = h2 ? tA2 : tA1;
    const u16* Wv = h2 ? W2  : W1;
    #pragma unroll
    for (int kk=0; kk<256; kk+=32){
      short8 af[2], bf[4];
      #pragma unroll
      for (int mi=0;mi<2;mi++)
        af[mi] = *(const short8*)((const char*)tA + swzb(wr + mi*16 + fr, kk*2 + quad*16));
      #pragma unroll
      for (int ni=0;ni<4;ni++)
        bf[ni] = *(const short8*)&Wv[(size_t)(wc + ni*16 + fr)*256 + kk + quad*8];
      #pragma unroll
      for (int mi=0;mi<2;mi++)
        #pragma unroll
        for (int ni=0;ni<4;ni++)
          acc[mi][ni] = __builtin_amdgcn_mfma_f32_16x16x32_bf16(af[mi], bf[ni], acc[mi][ni], 0, 0, 0);
    }
  }
}

#define ZERO_ACC2(a) { f32x4 _z = {0.f,0.f,0.f,0.f}; \
  _Pragma("unroll") for (int _i=0;_i<2;_i++) \
  _Pragma("unroll") for (int _j=0;_j<4;_j++) a[_i][_j] = _z; }

// ---- fused GIN MLP: G = relu(relu(G@W1^T+b1)@W2^T+b2), + BN partial sums ----
// 512 threads, 8 waves (2 row x 4 col groups), block = 64 rows x 256 cols.
__global__ __launch_bounds__(512, 2) void k_mlp(
    u16* __restrict__ Gp,
    const u16* __restrict__ w1, const void* __restrict__ b1,
    const u16* __restrict__ w2, const void* __restrict__ b2,
    long bO, float* __restrict__ bns, const int* __restrict__ dflag)
{
  const bool f32 = (*dflag != 0);
  __shared__ u16 Ag[64*256];
  __shared__ u16 At[64*256];
  const int tid = threadIdx.x;
  const size_t rowBase = (size_t)blockIdx.x * 64;
  const int lane = tid & 63, wave = tid >> 6;
  const int wr = (wave >> 2) * 32, wc = (wave & 3) * 64;
  const int fr = lane & 15, quad = lane >> 4;

  stage_tile64(Gp, Ag, rowBase, tid);
  __syncthreads();

  f32x4 acc[2][4];
  ZERO_ACC2(acc);
  gate_gemm<256>(acc, Ag, nullptr, w1, nullptr, wr, wc, fr, quad);

  // t = relu(acc + b1) -> LDS (swizzled, same layout as Ag)
  #pragma unroll
  for (int ni=0;ni<4;ni++){
    const int col = wc + ni*16 + fr;
    const float bv = ldext(b1, bO + col, f32);
    #pragma unroll
    for (int mi=0;mi<2;mi++)
      #pragma unroll
      for (int r4=0;r4<4;r4++){
        const int row = wr + mi*16 + quad*4 + r4;
        float v = fmaxf(acc[mi][ni][r4] + bv, 0.f);
        *(u16*)((char*)At + swzb(row, col*2)) = f2bf(v);
      }
  }
  __syncthreads();

  ZERO_ACC2(acc);
  gate_gemm<256>(acc, At, nullptr, w2, nullptr, wr, wc, fr, quad);

  // g = relu(acc + b2) -> global, plus per-column BN partial sums
  #pragma unroll
  for (int ni=0;ni<4;ni++){
    const int col = wc + ni*16 + fr;
    const float bv = ldext(b2, bO + col, f32);
    float s1 = 0.f, s2 = 0.f;
    #pragma unroll
    for (int mi=0;mi<2;mi++)
      #pragma unroll
      for (int r4=0;r4<4;r4++){
        const int row = wr + mi*16 + quad*4 + r4;
        const size_t grow = rowBase + row;
        float v = fmaxf(acc[mi][ni][r4] + bv, 0.f);
        Gp[grow*256 + col] = f2bf(v);
        if (grow < N_NODES){ s1 += v; s2 += v*v; }
      }
    s1 += __shfl_xor(s1, 16); s1 += __shfl_xor(s1, 32);   // reduce over quad
    s2 += __shfl_xor(s2, 16); s2 += __shfl_xor(s2, 32);
    if (quad == 0){
      unsafeAtomicAdd(&bns[col],       s1);
      unsafeAtomicAdd(&bns[256 + col], s2);
    }
  }
}

// ---- finalize BN stats -> per-column scale/shift ----------------------------
__global__ void k_bn_fin(const float* __restrict__ sums,
                         const void* __restrict__ gam, const void* __restrict__ bet,
                         long gO, float* __restrict__ ss,
                         const int* __restrict__ dflag){
  const bool f32 = (*dflag != 0);
  int c = threadIdx.x;                     // 256 threads
  float mu  = sums[c] * (1.f/N_NODES);
  float var = sums[256 + c] * (1.f/N_NODES) - mu*mu;
  float sc  = ldext(gam, gO + c, f32) * rsqrtf(fmaxf(var, 0.f) + LN_EPS);
  ss[2*c]     = sc;
  ss[2*c + 1] = ldext(bet, gO + c, f32) - mu*sc;
}

// ---- fused GRU: BN(G) on stage-in, 4 gate GEMMs, packed bf16 intermediates --
// out = (1-z)*tanh(in + r*hn) + z*h; block = 64 rows, wave = 32x64 outputs.
__global__ __launch_bounds__(512, 2) void k_gru(
    const u16* __restrict__ Gp, const u16* __restrict__ hp,
    const u16* __restrict__ wihl, const u16* __restrict__ whhl,
    const void* __restrict__ bih, const void* __restrict__ bhh,
    long bo, u16* __restrict__ outp, const float* __restrict__ ss,
    const int* __restrict__ dflag)
{
  const bool f32 = (*dflag != 0);
  __shared__ u16 Ag[64*256];
  __shared__ u16 Ah[64*256];
  const int tid = threadIdx.x;
  const size_t rowBase = (size_t)blockIdx.x * 64;
  const int lane = tid & 63, wave = tid >> 6;
  const int wr = (wave >> 2) * 32, wc = (wave & 3) * 64;
  const int fr = lane & 15, quad = lane >> 4;

  stage_tile64_bn(Gp, Ag, rowBase, tid, ss);   // Ag = BN(G)  (g input)
  stage_tile64(hp, Ah, rowBase, tid);
  __syncthreads();

  f32x4 acc[2][4];
  unsigned pk[2][4][2];                   // packed bf16 intermediate (2 vals/u32)

  // stage 1: hn = h@Whn^T + bhh_n  -> pk
  ZERO_ACC2(acc);
  gate_gemm<256>(acc, Ah, nullptr, whhl + 512*256, nullptr, wr, wc, fr, quad);
  #pragma unroll
  for (int ni=0;ni<4;ni++){
    const float bv = ldext(bhh, bo + 512 + wc + ni*16 + fr, f32);
    #pragma unroll
    for (int mi=0;mi<2;mi++)
      #pragma unroll
      for (int q=0;q<2;q++)
        pk[mi][ni][q] = (unsigned)f2bf(acc[mi][ni][2*q] + bv)
                      | ((unsigned)f2bf(acc[mi][ni][2*q+1] + bv) << 16);
  }

  // stage 2: r = sigm([g|h]@[Wir|Whr]^T + bir + bhr); pk <- r*hn
  ZERO_ACC2(acc);
  gate_gemm<512>(acc, Ag, Ah, wihl, whhl, wr, wc, fr, quad);
  #pragma unroll
  for (int ni=0;ni<4;ni++){
    const int col = wc + ni*16 + fr;
    const float bv = ldext(bih, bo + col, f32) + ldext(bhh, bo + col, f32);
    #pragma unroll
    for (int mi=0;mi<2;mi++)
      #pragma unroll
      for (int q=0;q<2;q++){
        float h0 = bf2f((u16)(pk[mi][ni][q] & 0xFFFFu));
        float h1 = bf2f((u16)(pk[mi][ni][q] >> 16));
        float r0 = sigm(acc[mi][ni][2*q]   + bv);
        float r1 = sigm(acc[mi][ni][2*q+1] + bv);
        pk[mi][ni][q] = (unsigned)f2bf(r0*h0) | ((unsigned)f2bf(r1*h1) << 16);
      }
  }

  // stage 3: n = tanh(g@Win^T + bin + r*hn); pk <- n
  ZERO_ACC2(acc);
  gate_gemm<256>(acc, Ag, nullptr, wihl + 512*256, nullptr, wr, wc, fr, quad);
  #pragma unroll
  for (int ni=0;ni<4;ni++){
    const float bv = ldext(bih, bo + 512 + wc + ni*16 + fr, f32);
    #pragma unroll
    for (int mi=0;mi<2;mi++)
      #pragma unroll
      for (int q=0;q<2;q++){
        float n0 = tanhf(acc[mi][ni][2*q]   + bv + bf2f((u16)(pk[mi][ni][q] & 0xFFFFu)));
        float n1 = tanhf(acc[mi][ni][2*q+1] + bv + bf2f((u16)(pk[mi][ni][q] >> 16)));
        pk[mi][ni][q] = (unsigned)f2bf(n0) | ((unsigned)f2bf(n1) << 16);
      }
  }

  // stage 4: z = sigm([g|h]@[Wiz|Whz]^T + biz + bhz); out = (1-z)*n + z*h
  ZERO_ACC2(acc);
  gate_gemm<512>(acc, Ag, Ah, wihl + 256*256, whhl + 256*256, wr, wc, fr, quad);
  #pragma unroll
  for (int ni=0;ni<4;ni++){
    const int col = wc + ni*16 + fr;
    const float bv = ldext(bih, bo + 256 + col, f32) + ldext(bhh, bo + 256 + col, f32);
    #pragma unroll
    for (int mi=0;mi<2;mi++)
      #pragma unroll
      for (int r4=0;r4<4;r4++){
        const int row = wr + mi*16 + quad*4 + r4;
        const float z = sigm(acc[mi][ni][r4] + bv);
        const unsigned pv = pk[mi][ni][r4 >> 1];
        const float nv = (r4 & 1) ? bf2f((u16)(pv >> 16)) : bf2f((u16)(pv & 0xFFFFu));
        const float hval = bf2f(*(const u16*)((const char*)Ah + swzb(row, col*2)));
        const float v = (1.f - z)*nv + z*hval;
        outp[(rowBase + row)*256 + col] = f2bf(v);
      }
  }
}

// ---- LayerNorm(hnew) + h/m/e update; layer2: m/e maxima via reduced atomics -
__global__ __launch_bounds__(256) void k_fin(
    const u16* __restrict__ hn, u16* __restrict__ h,
    u16* __restrict__ mb, u16* __restrict__ eb,
    const void* __restrict__ lng, const void* __restrict__ lnb,
    const int* __restrict__ batch, unsigned* __restrict__ outenc,
    int layer, int r0, const int* __restrict__ dflag)
{
  const bool f32 = (*dflag != 0);
  const int wave = threadIdx.x >> 6, lane = threadIdx.x & 63;
  const int n  = blockIdx.x*4 + wave;        // local row
  const int d0 = lane*4;
  const size_t rb = (size_t)n*256 + d0;
  float hv[4], mv[4], ev[4];
  ld4bf(&hn[rb], hv);
  if (layer != 0){
    ld4bf(&mb[rb], mv);
    ld4bf(&eb[rb], ev);
  }

  float s1 = 0.f, s2 = 0.f;
  #pragma unroll
  for (int j=0;j<4;j++){ s1 += hv[j]; s2 += hv[j]*hv[j]; }
  #pragma unroll
  for (int off=1; off<64; off<<=1){
    s1 += __shfl_xor(s1, off);
    s2 += __shfl_xor(s2, off);
  }
  const float mu   = s1 * (1.f/256.f);
  const float var  = s2 * (1.f/256.f) - mu*mu;
  const float rstd = rsqrtf(fmaxf(var, 0.f) + LN_EPS);

  float hl[4];
  #pragma unroll
  for (int j=0;j<4;j++){
    hl[j] = (hv[j]-mu)*rstd*ldext(lng, d0+j, f32) + ldext(lnb, d0+j, f32);
    if (layer == 0){ mv[j] = hl[j];  ev[j] = hl[j]; }
    else           { mv[j] *= hl[j]; ev[j] += hl[j]; }
  }
  *(ushort4*)&h[rb]  = make_ushort4(f2bf(hl[0]), f2bf(hl[1]), f2bf(hl[2]), f2bf(hl[3]));
  if (layer != 2){                            // m/e planes dead after layer 2
    *(ushort4*)&mb[rb] = make_ushort4(f2bf(mv[0]), f2bf(mv[1]), f2bf(mv[2]), f2bf(mv[3]));
    *(ushort4*)&eb[rb] = make_ushort4(f2bf(ev[0]), f2bf(ev[1]), f2bf(ev[2]), f2bf(ev[3]));
  }

  if (layer == 2){
    __shared__ float redm[1024], rede[1024];
    __shared__ int bgs[4];
    const int ng = r0 + n;
    if (lane == 0) bgs[wave] = (ng < N_NODES) ? batch[ng] : -1;
    #pragma unroll
    for (int j=0;j<4;j++){ redm[wave*256 + d0 + j] = mv[j]; rede[wave*256 + d0 + j] = ev[j]; }
    __syncthreads();
    const bool uniform = (bgs[0] >= 0) && bgs[0]==bgs[1] && bgs[1]==bgs[2] && bgs[2]==bgs[3];
    if (uniform){
      const int c = threadIdx.x;              // 256 threads = 256 cols
      float mm = fmaxf(fmaxf(redm[c], redm[256+c]), fmaxf(redm[512+c], redm[768+c]));
      float me = fmaxf(fmaxf(rede[c], rede[256+c]), fmaxf(rede[512+c], rede[768+c]));
      unsigned* ob = &outenc[(size_t)bgs[0]*512];
      atomicMax(&ob[c],       enc_f(mm));
      atomicMax(&ob[256 + c], enc_f(me));
    } else {
      const int bg = (ng < N_NODES) ? batch[ng] : -1;
      if (bg >= 0){
        unsigned* ob = &outenc[(size_t)bg*512 + d0];
        atomicMax(&ob[0], enc_f(mv[0])); atomicMax(&ob[1], enc_f(mv[1]));
        atomicMax(&ob[2], enc_f(mv[2])); atomicMax(&ob[3], enc_f(mv[3]));
        atomicMax(&ob[256+0], enc_f(ev[0])); atomicMax(&ob[256+1], enc_f(ev[1]));
        atomicMax(&ob[256+2], enc_f(ev[2])); atomicMax(&ob[256+3], enc_f(ev[3]));
      }
    }
  }
}

// ---- atomic-free segment max over sorted batch: h plane -> out slice --------
__global__ __launch_bounds__(256) void k_segmax(
    const u16* __restrict__ plane, void* __restrict__ out, long slice,
    const int* __restrict__ batch, const int* __restrict__ dflag)
{
  const bool f32 = (*dflag != 0);
  const int g = blockIdx.x*4 + (threadIdx.x >> 6);
  const int lane = threadIdx.x & 63;
  int lo = 0, hi = N_NODES;
  while (lo < hi){ int mid = (lo + hi) >> 1; if (batch[mid] < g) lo = mid + 1; else hi = mid; }
  const int s = lo;
  hi = N_NODES;
  while (lo < hi){ int mid = (lo + hi) >> 1; if (batch[mid] < g + 1) lo = mid + 1; else hi = mid; }
  const int epos = lo;

  const float NINF = __uint_as_float(0xFF800000u);
  float a0=NINF, a1=NINF, a2=NINF, a3=NINF;
  for (int r = s; r < epos; r++){
    ushort4 v = *(const ushort4*)&plane[(size_t)r*256 + lane*4];
    a0 = fmaxf(a0, bf2f(v.x)); a1 = fmaxf(a1, bf2f(v.y));
    a2 = fmaxf(a2, bf2f(v.z)); a3 = fmaxf(a3, bf2f(v.w));
  }
  const long ob = (long)g*1280 + slice + lane*4;
  if (f32){
    float* o = (float*)out + ob;
    o[0]=a0; o[1]=a1; o[2]=a2; o[3]=a3;
  } else {
    *(ushort4*)((u16*)out + ob) = make_ushort4(f2bf(a0), f2bf(a1), f2bf(a2), f2bf(a3));
  }
}

// decode m/e maxima: oenc[g*512 + c] -> out[g*1280 + 768 + c]
__global__ void k_decode_me(const unsigned* __restrict__ enc, void* __restrict__ out,
                            const int* __restrict__ dflag){
  const bool f32 = (*dflag != 0);
  int i = blockIdx.x*256 + threadIdx.x;      // 4096*512
  int g = i >> 9, c = i & 511;
  unsigned u = enc[i];
  float f = (u == 0u) ? __uint_as_float(0xFF800000u) : dec_f(u);  // empty -> -inf
  long o = (long)g*1280 + 768 + c;
  if (f32) ((float*)out)[o] = f;
  else     ((u16*)out)[o]   = f2bf(f);
}

// ---- launcher ---------------------------------------------------------------
extern "C" void kernel_launch(void* const* d_in, const int* in_sizes, int n_in,
                              void* d_out, int out_size, void* d_ws, size_t ws_size,
                              hipStream_t stream)
{
  const void* x   = d_in[0];
  const void* l1w = d_in[1];  const void* l1b = d_in[2];
  const void* l2w = d_in[3];  const void* l2b = d_in[4];
  const void* bng = d_in[5];  const void* bnb = d_in[6];
  const void* wih = d_in[7];  const void* whh = d_in[8];
  const void* bih = d_in[9];  const void* bhh = d_in[10];
  const void* lng = d_in[11]; const void* lnb = d_in[12];
  const int* ei    = (const int*)d_in[13];
  const int* batch = (const int*)d_in[14];
  (void)in_sizes; (void)n_in; (void)out_size;

  const size_t PL = S_EL * 2;            // bf16 plane bytes (51.25 MB)
  char* p = (char*)d_ws; size_t off = 0;
  auto take = [&](size_t b){ void* q = p + off; off += (b + 255) & ~(size_t)255; return q; };
  u16*      h    = (u16*)take(PL);
  u16*      m    = (u16*)take(PL);
  u16*      e    = (u16*)take(PL);
  u16*      G    = (u16*)take(PL);       // agg -> g0 -> g
  unsigned* oenc = (unsigned*)take(OENC_B);
  float*    bns  = (float*)take(512*4);
  float*    bss  = (float*)take(512*4);  // BN scale/shift interleaved
  int*      dflg = (int*)take(256);
  int*      cnt  = (int*)take((size_t)N_NODES*4);
  int*      bkt  = (int*)take((size_t)N_NODES*CAP*4);   // 12.8 MB
  int*      ovf  = (int*)take((size_t)N_EDGES*4);       // worst-case overflow list
  int*      ovfc = (int*)take(256);
  // bf16 weight copies (all layers): lin1|lin2: 3*64K, wih|whh: 3*192K elems
  u16*      wb1  = (u16*)take((size_t)3*65536*2);
  u16*      wb2  = (u16*)take((size_t)3*65536*2);
  u16*      wbih = (u16*)take((size_t)3*196608*2);
  u16*      wbhh = (u16*)take((size_t)3*196608*2);
  // hnew chunk scratch sized from the actual remaining workspace
  const size_t TILE_B = 128*256*2;       // one 128-row bf16 tile (64 KB)
  size_t rem = (ws_size > off + TILE_B) ? (ws_size - off) : TILE_B;
  int CT = (int)(rem / TILE_B);          // tiles per chunk
  if (CT < 1) CT = 1;
  if (CT > N_TILES) CT = N_TILES;
  u16* S2 = (u16*)take((size_t)CT*TILE_B);

  k_detect<<<1, 64, 0, stream>>>((const unsigned*)x, dflg);
  hipMemsetAsync(oenc, 0, OENC_B, stream);
  hipMemsetAsync(cnt, 0, (size_t)N_NODES*4, stream);
  hipMemsetAsync(ovfc, 0, 4, stream);
  k_h_init <<<S_EL/8/256, 256, 0, stream>>>(x, h, dflg);
  k_bucket_build<<<(N_EDGES + 255)/256, 256, 0, stream>>>(ei, cnt, bkt, ovf, ovfc);
  k_wconv<<< 96, 256, 0, stream>>>(l1w, wb1,  dflg);   // 3*65536/8/256
  k_wconv<<< 96, 256, 0, stream>>>(l2w, wb2,  dflg);
  k_wconv<<<288, 256, 0, stream>>>(wih, wbih, dflg);   // 3*196608/8/256
  k_wconv<<<288, 256, 0, stream>>>(whh, wbhh, dflg);

  for (int l = 0; l < 3; l++){
    const long bo = (long)l*768;
    hipMemsetAsync(bns, 0, 512*4, stream);
    k_gather<<<(M_PAD*128)/256, 256, 0, stream>>>((const unsigned*)h, cnt, bkt, (unsigned*)G);
    k_ovf_scatter<<<512, 256, 0, stream>>>((const unsigned*)h, ei, ovf, ovfc, (unsigned*)G);

    // fused MLP (lin1+relu+lin2+relu) in-place on G, with fused BN stats
    k_mlp<<<N_TILES*2, 512, 0, stream>>>(G, wb1 + (size_t)l*65536, l1b,
                                         wb2 + (size_t)l*65536, l2b,
                                         (long)l*256, bns, dflg);
    k_bn_fin<<<1, 256, 0, stream>>>(bns, bng, bnb, (long)l*256, bss, dflg);

    for (int t0 = 0; t0 < N_TILES; t0 += CT){
      const int ct = min(CT, N_TILES - t0);
      const size_t o2 = (size_t)t0*128*256;
      k_gru<<<ct*2, 512, 0, stream>>>(G + o2, h + o2,
                                      wbih + (size_t)l*196608, wbhh + (size_t)l*196608,
                                      bih, bhh, bo, S2, bss, dflg);
      k_fin<<<ct*128/4, 256, 0, stream>>>(S2, h + o2, m + o2, e + o2,
                                          lng, lnb, batch, oenc, l, t0*128, dflg);
    }
    k_segmax<<<N_GRAPH/4, 256, 0, stream>>>(h, d_out, (long)l*256, batch, dflg);
  }
  k_decode_me<<<(N_GRAPH*512)/256, 256, 0, stream>>>(oenc, d_out, dflg);
}